// Round 1
// baseline (416.645 us; speedup 1.0000x reference)
//
#include <hip/hip_runtime.h>
#include <hip/hip_bf16.h>
#include <cstdint>
#include <cstddef>

typedef __bf16 bf16_t;
typedef __bf16 bf16x4 __attribute__((ext_vector_type(4)));
typedef __bf16 bf16x8 __attribute__((ext_vector_type(8)));
typedef float f32x4 __attribute__((ext_vector_type(4)));

#define BM 128
#define BN 128
#define BK 32

// ---------------------------------------------------------------------------
// x fp32 -> bf16, vectorized (G13)
// ---------------------------------------------------------------------------
__global__ __launch_bounds__(256) void cvt_x_kernel(const float* __restrict__ x,
                                                    bf16_t* __restrict__ xb, int n4) {
    int idx = blockIdx.x * blockDim.x + threadIdx.x;
    int stride = gridDim.x * blockDim.x;
    const f32x4* xv = (const f32x4*)x;
    bf16x4* ov = (bf16x4*)xb;
    for (int i = idx; i < n4; i += stride) {
        f32x4 v = xv[i];
        bf16x4 o;
        o[0] = (bf16_t)v[0];
        o[1] = (bf16_t)v[1];
        o[2] = (bf16_t)v[2];
        o[3] = (bf16_t)v[3];
        ov[i] = o;
    }
}

// ---------------------------------------------------------------------------
// Build Mt[n][k] = sign(i,j) * W_src(i,j)[k%1024][n%1024],  i=k>>10, j=n>>10
// Stored transposed ([N][K]) so the GEMM's B-fragment reads are K-contiguous.
// LDS transpose tile for coalesced global read AND write.
// ---------------------------------------------------------------------------
__global__ __launch_bounds__(256) void pack_w_kernel(const float* __restrict__ Wa,
                                                     const float* __restrict__ Wb,
                                                     const float* __restrict__ Wc,
                                                     const float* __restrict__ Wd,
                                                     bf16_t* __restrict__ Mt) {
    __shared__ float tile[64][65];  // +1 pad: conflict-free transpose
    const int kb = blockIdx.x * 64;
    const int nb = blockIdx.y * 64;
    const int i = kb >> 10;  // input quaternion component
    const int j = nb >> 10;  // output quaternion component

    const float* W[4] = {Wa, Wb, Wc, Wd};
    const int srcIdx[4][4] = {{0, 1, 2, 3}, {1, 0, 3, 2}, {2, 3, 0, 1}, {3, 2, 1, 0}};
    const float sgn[4][4] = {{1.f, 1.f, 1.f, 1.f},
                             {-1.f, 1.f, -1.f, 1.f},
                             {-1.f, 1.f, 1.f, -1.f},
                             {-1.f, -1.f, 1.f, 1.f}};
    const float* Ws = W[srcIdx[i][j]];
    const float s = sgn[i][j];

    const int kq = kb & 1023;
    const int nq = nb & 1023;
    const int tx = threadIdx.x & 63;
    const int ty = threadIdx.x >> 6;

    for (int r = ty; r < 64; r += 4)
        tile[r][tx] = Ws[(size_t)(kq + r) * 1024 + (nq + tx)];
    __syncthreads();
    for (int r = ty; r < 64; r += 4)
        Mt[(size_t)(nb + r) * 4096 + (kb + tx)] = (bf16_t)(s * tile[tx][r]);
}

// ---------------------------------------------------------------------------
// C[M][N] = A[M][K] * Bt[N][K]^T + bias   (m97-structure 128x128 tile, BK=32)
// 4 waves, each owns a 64x64 output sub-tile = 4x4 frags of 16x16x32 bf16 MFMA.
// global_load_lds width=16 staging, 2 barriers per K-step.
// ---------------------------------------------------------------------------
__global__ __launch_bounds__(256) void qgemm_kernel(const bf16_t* __restrict__ A,
                                                    const bf16_t* __restrict__ Bt,
                                                    const float* __restrict__ bias,
                                                    float* __restrict__ C,
                                                    int M, int N, int K) {
    __shared__ __align__(16) bf16_t As[BM * BK];  // 8 KB, linear [row][k]
    __shared__ __align__(16) bf16_t Bs[BN * BK];  // 8 KB, linear [col][k]

    const int t = threadIdx.x;
    const int wave = t >> 6;
    const int lane = t & 63;
    const int l15 = lane & 15;
    const int l4 = lane >> 4;
    const int brow = blockIdx.y * BM;
    const int bcol = blockIdx.x * BN;
    const int wr = wave >> 1;  // wave row (0..1)
    const int wc = wave & 1;   // wave col (0..1)

    f32x4 acc[4][4] = {};

    for (int k0 = 0; k0 < K; k0 += BK) {
        // ---- stage A,B tiles: 8KB each = 2 rounds x 256 threads x 16B ----
#pragma unroll
        for (int q = 0; q < 2; ++q) {
            const int ldsbase = q * 4096 + wave * 1024;  // wave-uniform byte base
            const int o = ldsbase + lane * 16;           // this lane's dest byte
            const int row = o >> 6;                      // 64 B per row (BK=32 bf16)
            const int kk = (o & 63) >> 1;
            const bf16_t* ga = A + (size_t)(brow + row) * K + (k0 + kk);
            const bf16_t* gb = Bt + (size_t)(bcol + row) * K + (k0 + kk);
            __builtin_amdgcn_global_load_lds(
                (const __attribute__((address_space(1))) void*)ga,
                (__attribute__((address_space(3))) void*)((char*)As + ldsbase), 16, 0, 0);
            __builtin_amdgcn_global_load_lds(
                (const __attribute__((address_space(1))) void*)gb,
                (__attribute__((address_space(3))) void*)((char*)Bs + ldsbase), 16, 0, 0);
        }
        __syncthreads();  // drains vmcnt -> tiles ready

        // ---- fragments: A row = l15, k = l4*8+j ; B col = l15, k = l4*8+j ----
        bf16x8 af[4], bfr[4];
#pragma unroll
        for (int m = 0; m < 4; ++m)
            af[m] = *(const bf16x8*)&As[(wr * 64 + m * 16 + l15) * BK + l4 * 8];
#pragma unroll
        for (int n = 0; n < 4; ++n)
            bfr[n] = *(const bf16x8*)&Bs[(wc * 64 + n * 16 + l15) * BK + l4 * 8];

#pragma unroll
        for (int m = 0; m < 4; ++m)
#pragma unroll
            for (int n = 0; n < 4; ++n)
                acc[m][n] = __builtin_amdgcn_mfma_f32_16x16x32_bf16(af[m], bfr[n],
                                                                   acc[m][n], 0, 0, 0);
        __syncthreads();  // WAR: compute done before next stage overwrites
    }

    // ---- epilogue: C/D layout col = lane&15, row = (lane>>4)*4 + i (m89) ----
#pragma unroll
    for (int n = 0; n < 4; ++n) {
        const int col = bcol + wc * 64 + n * 16 + l15;
        const float bv = bias[col];
#pragma unroll
        for (int m = 0; m < 4; ++m) {
            const f32x4 v = acc[m][n];
            const int row0 = brow + wr * 64 + m * 16 + l4 * 4;
#pragma unroll
            for (int i = 0; i < 4; ++i)
                C[(size_t)(row0 + i) * N + col] = v[i] + bv;
        }
    }
}

// ---------------------------------------------------------------------------
extern "C" void kernel_launch(void* const* d_in, const int* in_sizes, int n_in,
                              void* d_out, int out_size, void* d_ws, size_t ws_size,
                              hipStream_t stream) {
    const float* x = (const float*)d_in[0];
    const float* Wa = (const float*)d_in[1];
    const float* Wb = (const float*)d_in[2];
    const float* Wc = (const float*)d_in[3];
    const float* Wd = (const float*)d_in[4];
    const float* bias = (const float*)d_in[5];
    float* out = (float*)d_out;

    const int M = 8192, N = 4096, K = 4096;

    // workspace: xb = bf16 x [M][K] (67.1 MB), Mt = bf16 [N][K] (33.5 MB)
    bf16_t* xb = (bf16_t*)d_ws;
    bf16_t* Mt = xb + (size_t)M * K;

    cvt_x_kernel<<<4096, 256, 0, stream>>>(x, xb, (M * K) / 4);
    pack_w_kernel<<<dim3(64, 64), 256, 0, stream>>>(Wa, Wb, Wc, Wd, Mt);
    qgemm_kernel<<<dim3(N / BN, M / BM), 256, 0, stream>>>(xb, Mt, bias, out, M, N, K);
}

// Round 2
// 301.939 us; speedup vs baseline: 1.3799x; 1.3799x over previous
//
#include <hip/hip_runtime.h>
#include <hip/hip_bf16.h>
#include <cstdint>
#include <cstddef>

typedef __bf16 bf16_t;
typedef __bf16 bf16x4 __attribute__((ext_vector_type(4)));
typedef __bf16 bf16x8 __attribute__((ext_vector_type(8)));
typedef float f32x4 __attribute__((ext_vector_type(4)));

#define GLD16(src, dst)                                                       \
    __builtin_amdgcn_global_load_lds(                                         \
        (const __attribute__((address_space(1))) void*)(src),                 \
        (__attribute__((address_space(3))) void*)(dst), 16, 0, 0)

#define BAR() __builtin_amdgcn_s_barrier()
#define WAIT_LGKM0()                                                          \
    do {                                                                      \
        asm volatile("s_waitcnt lgkmcnt(0)" ::: "memory");                    \
        __builtin_amdgcn_sched_barrier(0);                                    \
    } while (0)
#define WAIT_VM4() asm volatile("s_waitcnt vmcnt(4)" ::: "memory")
#define WAIT_VM0() asm volatile("s_waitcnt vmcnt(0)" ::: "memory")

// ---------------------------------------------------------------------------
// x fp32 -> bf16, vectorized (G13)
// ---------------------------------------------------------------------------
__global__ __launch_bounds__(256) void cvt_x_kernel(const float* __restrict__ x,
                                                    bf16_t* __restrict__ xb, int n4) {
    int idx = blockIdx.x * blockDim.x + threadIdx.x;
    int stride = gridDim.x * blockDim.x;
    const f32x4* xv = (const f32x4*)x;
    bf16x4* ov = (bf16x4*)xb;
    for (int i = idx; i < n4; i += stride) {
        f32x4 v = xv[i];
        bf16x4 o;
        o[0] = (bf16_t)v[0];
        o[1] = (bf16_t)v[1];
        o[2] = (bf16_t)v[2];
        o[3] = (bf16_t)v[3];
        ov[i] = o;
    }
}

// ---------------------------------------------------------------------------
// Build Mt[n][k] (bf16, [N][K]) from the quaternion Hamilton block structure.
// ---------------------------------------------------------------------------
__global__ __launch_bounds__(256) void pack_w_kernel(const float* __restrict__ Wa,
                                                     const float* __restrict__ Wb,
                                                     const float* __restrict__ Wc,
                                                     const float* __restrict__ Wd,
                                                     bf16_t* __restrict__ Mt) {
    __shared__ float tile[64][65];
    const int kb = blockIdx.x * 64;
    const int nb = blockIdx.y * 64;
    const int i = kb >> 10;
    const int j = nb >> 10;

    const float* W[4] = {Wa, Wb, Wc, Wd};
    const int srcIdx[4][4] = {{0, 1, 2, 3}, {1, 0, 3, 2}, {2, 3, 0, 1}, {3, 2, 1, 0}};
    const float sgn[4][4] = {{1.f, 1.f, 1.f, 1.f},
                             {-1.f, 1.f, -1.f, 1.f},
                             {-1.f, 1.f, 1.f, -1.f},
                             {-1.f, -1.f, 1.f, 1.f}};
    const float* Ws = W[srcIdx[i][j]];
    const float s = sgn[i][j];

    const int kq = kb & 1023;
    const int nq = nb & 1023;
    const int tx = threadIdx.x & 63;
    const int ty = threadIdx.x >> 6;

    for (int r = ty; r < 64; r += 4)
        tile[r][tx] = Ws[(size_t)(kq + r) * 1024 + (nq + tx)];
    __syncthreads();
    for (int r = ty; r < 64; r += 4)
        Mt[(size_t)(nb + r) * 4096 + (kb + tx)] = (bf16_t)(s * tile[tx][r]);
}

// ---------------------------------------------------------------------------
// 256x256 8-phase GEMM (T1+T2+T3+T4+T5), C = A[M][K] * Bt[N][K]^T + bias.
// 512 threads = 8 waves (2Mx4N), each owns 128x64. BK=64 as 2 K32 chunks.
// LDS 128 KiB: A dbuf [0,64K), B dbuf [64K,128K); each buf [c][256 rows][32] bf16
// with XOR swizzle f(a)=a^((a>>9&1)<<5)^((a>>8&1)<<4) (2-way conflict-free reads),
// realized as linear gload_lds dest + pre-swizzled global source (rule 21).
// ---------------------------------------------------------------------------
__global__ __launch_bounds__(512, 2) void qgemm_kernel(const bf16_t* __restrict__ A,
                                                       const bf16_t* __restrict__ Bt,
                                                       const float* __restrict__ bias,
                                                       float* __restrict__ C) {
    constexpr int N = 4096, K = 4096;
    constexpr int NT = K / 64;
    extern __shared__ __align__(16) char lds[];

    const int tid = threadIdx.x;
    const int w = tid >> 6;
    const int lane = tid & 63;
    const int l15 = lane & 15, l4 = lane >> 4;
    const int wr = w >> 2, wc = w & 3;  // 2 x 4 wave grid

    // XCD-aware swizzle (512 = 8*64, bijective)
    const int wg = blockIdx.x;
    const int swz = (wg & 7) * 64 + (wg >> 3);
    const int brow = (swz >> 4) * 256;  // 32 tile rows
    const int bcol = (swz & 15) * 256;  // 16 tile cols

    // swizzled ds_read lane offset: row=l15, 16B block = l4 ^ (l15>>2)
    const int rdoff = l15 * 64 + ((l4 ^ (l15 >> 2)) & 3) * 16;
    // staging: lane -> row srow (4 lanes/row), global 16B-block permuted by row bits 2-3
    const int srow = lane >> 2;
    const int kbp = (lane & 3) ^ ((lane >> 4) & 3);

    auto stageA = [&](int buf, int h, int tt) {
#pragma unroll
        for (int c = 0; c < 2; ++c) {
            const bf16_t* src = A + (size_t)(brow + h * 128 + w * 16 + srow) * K +
                                tt * 64 + c * 32 + kbp * 8;
            GLD16(src, lds + buf * 32768 + c * 16384 + (h * 128 + w * 16) * 64);
        }
    };
    auto stageB = [&](int buf, int h, int tt) {
#pragma unroll
        for (int c = 0; c < 2; ++c) {
            const bf16_t* src = Bt + (size_t)(bcol + h * 128 + w * 16 + srow) * K +
                                tt * 64 + c * 32 + kbp * 8;
            GLD16(src, lds + 65536 + buf * 32768 + c * 16384 + (h * 128 + w * 16) * 64);
        }
    };

    f32x4 acc[8][4] = {};
    bf16x8 a[4][2], b0[2][2], b1[2][2];

    auto ldA = [&](int buf, int mh) {
#pragma unroll
        for (int m = 0; m < 4; ++m)
#pragma unroll
            for (int c = 0; c < 2; ++c)
                a[m][c] = *(const bf16x8*)(lds + buf * 32768 + c * 16384 +
                                           (wr * 128 + mh * 64 + m * 16) * 64 + rdoff);
    };
    auto ldB = [&](int buf, int nh, bf16x8(&b)[2][2]) {
#pragma unroll
        for (int n = 0; n < 2; ++n)
#pragma unroll
            for (int c = 0; c < 2; ++c)
                b[n][c] = *(const bf16x8*)(lds + 65536 + buf * 32768 + c * 16384 +
                                           (wc * 64 + nh * 32 + n * 16) * 64 + rdoff);
    };
    auto mmac = [&](int mh, int nh, bf16x8(&b)[2][2]) {
        __builtin_amdgcn_s_setprio(1);
#pragma unroll
        for (int m = 0; m < 4; ++m)
#pragma unroll
            for (int n = 0; n < 2; ++n)
#pragma unroll
                for (int c = 0; c < 2; ++c)
                    acc[mh * 4 + m][nh * 2 + n] = __builtin_amdgcn_mfma_f32_16x16x32_bf16(
                        a[m][c], b[n][c], acc[mh * 4 + m][nh * 2 + n], 0, 0, 0);
        __builtin_amdgcn_s_setprio(0);
    };

    // prologue: tile0 all 4 half-tiles + tile1 Bh0, Ah0 (12 loads); leave tile1's in flight
    stageA(0, 0, 0);
    stageA(0, 1, 0);
    stageB(0, 0, 0);
    stageB(0, 1, 0);
    stageB(1, 0, 1);
    stageA(1, 0, 1);
    WAIT_VM4();
    BAR();

    for (int tt = 0; tt < NT; ++tt) {
        const int cur = tt & 1;
        // phase 0: quadrant (mh=0, nh=0); stage Ah1 for t+1 (idle buffer)
        ldA(cur, 0);
        ldB(cur, 0, b0);
        if (tt + 1 < NT) stageA(cur ^ 1, 1, tt + 1);
        BAR();
        WAIT_LGKM0();
        mmac(0, 0, b0);
        BAR();
        // phase 1: (0,1); stage Bh1 for t+1 (idle buffer)
        ldB(cur, 1, b1);
        if (tt + 1 < NT) stageB(cur ^ 1, 1, tt + 1);
        BAR();
        WAIT_LGKM0();
        mmac(0, 1, b1);
        BAR();
        // phase 2: (1,1); stage Bh0 for t+2 (live buffer, B reads done at p1)
        ldA(cur, 1);
        if (tt + 2 < NT) stageB(cur, 0, tt + 2);
        BAR();
        WAIT_LGKM0();
        mmac(1, 1, b1);
        BAR();
        // phase 3: (1,0); stage Ah0 for t+2 (live buffer, A reads done at p2)
        if (tt + 2 < NT) stageA(cur, 0, tt + 2);
        BAR();
        WAIT_LGKM0();
        mmac(1, 0, b0);
        // counted vmcnt: t+1 fully landed, t+2's Bh0/Ah0 (4 loads) stay in flight
        if (tt + 2 < NT) {
            WAIT_VM4();
        } else {
            WAIT_VM0();  // tail: nothing newer in flight; must drain t+1 fully
        }
        BAR();
    }

    // epilogue: C/D layout col = lane&15, row = (lane>>4)*4 + i
#pragma unroll
    for (int n = 0; n < 4; ++n) {
        const int col = bcol + wc * 64 + n * 16 + l15;
        const float bv = bias[col];
#pragma unroll
        for (int m = 0; m < 8; ++m) {
            const int row0 = brow + wr * 128 + m * 16 + l4 * 4;
            const f32x4 v = acc[m][n];
#pragma unroll
            for (int i = 0; i < 4; ++i)
                C[(size_t)(row0 + i) * N + col] = v[i] + bv;
        }
    }
}

// ---------------------------------------------------------------------------
extern "C" void kernel_launch(void* const* d_in, const int* in_sizes, int n_in,
                              void* d_out, int out_size, void* d_ws, size_t ws_size,
                              hipStream_t stream) {
    const float* x = (const float*)d_in[0];
    const float* Wa = (const float*)d_in[1];
    const float* Wb = (const float*)d_in[2];
    const float* Wc = (const float*)d_in[3];
    const float* Wd = (const float*)d_in[4];
    const float* bias = (const float*)d_in[5];
    float* out = (float*)d_out;

    const int M = 8192, N = 4096, K = 4096;

    bf16_t* xb = (bf16_t*)d_ws;                 // [M][K] bf16
    bf16_t* Mt = xb + (size_t)M * K;            // [N][K] bf16

    cvt_x_kernel<<<4096, 256, 0, stream>>>(x, xb, (M * K) / 4);
    pack_w_kernel<<<dim3(64, 64), 256, 0, stream>>>(Wa, Wb, Wc, Wd, Mt);

    (void)hipFuncSetAttribute((const void*)qgemm_kernel,
                              hipFuncAttributeMaxDynamicSharedMemorySize, 131072);
    qgemm_kernel<<<dim3((M / 256) * (N / 256)), 512, 131072, stream>>>(xb, Mt, bias, out);
}

// Round 3
// 284.713 us; speedup vs baseline: 1.4634x; 1.0605x over previous
//
#include <hip/hip_runtime.h>
#include <hip/hip_bf16.h>
#include <cstdint>
#include <cstddef>

typedef __bf16 bf16_t;
typedef __bf16 bf16x4 __attribute__((ext_vector_type(4)));
typedef __bf16 bf16x8 __attribute__((ext_vector_type(8)));
typedef float f32x4 __attribute__((ext_vector_type(4)));

#define GLD16(src, dst)                                                       \
    __builtin_amdgcn_global_load_lds(                                         \
        (const __attribute__((address_space(1))) void*)(src),                 \
        (__attribute__((address_space(3))) void*)(dst), 16, 0, 0)

#define BAR() __builtin_amdgcn_s_barrier()
#define WAIT_LGKM0()                                                          \
    do {                                                                      \
        asm volatile("s_waitcnt lgkmcnt(0)" ::: "memory");                    \
        __builtin_amdgcn_sched_barrier(0);                                    \
    } while (0)
#define WAIT_VM4() asm volatile("s_waitcnt vmcnt(4)" ::: "memory")
#define WAIT_VM0() asm volatile("s_waitcnt vmcnt(0)" ::: "memory")

// ---------------------------------------------------------------------------
// x fp32 -> bf16, vectorized (G13)
// ---------------------------------------------------------------------------
__global__ __launch_bounds__(256) void cvt_x_kernel(const float* __restrict__ x,
                                                    bf16_t* __restrict__ xb, int n4) {
    int idx = blockIdx.x * blockDim.x + threadIdx.x;
    int stride = gridDim.x * blockDim.x;
    const f32x4* xv = (const f32x4*)x;
    bf16x4* ov = (bf16x4*)xb;
    for (int i = idx; i < n4; i += stride) {
        f32x4 v = xv[i];
        bf16x4 o;
        o[0] = (bf16_t)v[0];
        o[1] = (bf16_t)v[1];
        o[2] = (bf16_t)v[2];
        o[3] = (bf16_t)v[3];
        ov[i] = o;
    }
}

// ---------------------------------------------------------------------------
// Build Mt[n][k] (bf16, [N][K]) from the quaternion Hamilton block structure.
// ---------------------------------------------------------------------------
__global__ __launch_bounds__(256) void pack_w_kernel(const float* __restrict__ Wa,
                                                     const float* __restrict__ Wb,
                                                     const float* __restrict__ Wc,
                                                     const float* __restrict__ Wd,
                                                     bf16_t* __restrict__ Mt) {
    __shared__ float tile[64][65];
    const int kb = blockIdx.x * 64;
    const int nb = blockIdx.y * 64;
    const int i = kb >> 10;
    const int j = nb >> 10;

    const float* W[4] = {Wa, Wb, Wc, Wd};
    const int srcIdx[4][4] = {{0, 1, 2, 3}, {1, 0, 3, 2}, {2, 3, 0, 1}, {3, 2, 1, 0}};
    const float sgn[4][4] = {{1.f, 1.f, 1.f, 1.f},
                             {-1.f, 1.f, -1.f, 1.f},
                             {-1.f, 1.f, 1.f, -1.f},
                             {-1.f, -1.f, 1.f, 1.f}};
    const float* Ws = W[srcIdx[i][j]];
    const float s = sgn[i][j];

    const int kq = kb & 1023;
    const int nq = nb & 1023;
    const int tx = threadIdx.x & 63;
    const int ty = threadIdx.x >> 6;

    for (int r = ty; r < 64; r += 4)
        tile[r][tx] = Ws[(size_t)(kq + r) * 1024 + (nq + tx)];
    __syncthreads();
    for (int r = ty; r < 64; r += 4)
        Mt[(size_t)(nb + r) * 4096 + (kb + tx)] = (bf16_t)(s * tile[tx][r]);
}

// ---------------------------------------------------------------------------
// 256x256 8-phase GEMM, C = A[M][K] * Bt[N][K]^T + bias.
// 512 threads = 8 waves (2Mx4N), each owns 128x64. BK=64, one 128B row per tile row.
// LDS 128 KiB: A dbuf [0,64K), B dbuf [64K,128K); half-tile = [128 rows][64 k] bf16.
// T2 swizzle (G4 recipe): 16B-block' = block ^ (row&7). Write side: linear
// global_load_lds dest + inverse-permuted per-lane GLOBAL k-block (rule 21).
// Read side: ds_read_b128 at row*128 + ((4c+l4)^(l15&7))*16.
// ---------------------------------------------------------------------------
__global__ __launch_bounds__(512, 2) void qgemm_kernel(const bf16_t* __restrict__ A,
                                                       const bf16_t* __restrict__ Bt,
                                                       const float* __restrict__ bias,
                                                       float* __restrict__ C) {
    constexpr int N = 4096, K = 4096;
    constexpr int NT = K / 64;
    extern __shared__ __align__(16) char lds[];

    const int tid = threadIdx.x;
    const int w = tid >> 6;
    const int lane = tid & 63;
    const int l15 = lane & 15, l4 = lane >> 4;
    const int wr = w >> 2, wc = w & 3;  // 2 x 4 wave grid

    // XCD-aware swizzle (512 = 8*64, bijective)
    const int wg = blockIdx.x;
    const int swz = (wg & 7) * 64 + (wg >> 3);
    const int brow = (swz >> 4) * 256;  // 32 tile rows
    const int bcol = (swz & 15) * 256;  // 16 tile cols

    // staging: each wave stages its 16 rows as 2 x (8 rows x 128B) GLD.
    // LDS stores k-block' = kb ^ (row&7); dest is linear, so the GLOBAL
    // source k-block for lane slot (lane&7) at row (lane>>3) is the inverse:
    const int srow = lane >> 3;                    // row within 8-row group
    const int skb = (lane & 7) ^ (lane >> 3);      // global 16B k-block

    auto stageA = [&](int buf, int h, int tt) {
#pragma unroll
        for (int q = 0; q < 2; ++q) {
            const bf16_t* src = A + (size_t)(brow + h * 128 + w * 16 + q * 8 + srow) * K +
                                tt * 64 + skb * 8;
            GLD16(src, lds + buf * 32768 + h * 16384 + w * 2048 + q * 1024);
        }
    };
    auto stageB = [&](int buf, int h, int tt) {
#pragma unroll
        for (int q = 0; q < 2; ++q) {
            const bf16_t* src = Bt + (size_t)(bcol + h * 128 + w * 16 + q * 8 + srow) * K +
                                tt * 64 + skb * 8;
            GLD16(src, lds + 65536 + buf * 32768 + h * 16384 + w * 2048 + q * 1024);
        }
    };

    f32x4 acc[8][4] = {};
    bf16x8 a[4][2], b0[2][2], b1[2][2];

    // swizzled read: fragment (row R, k-chunk c): 16B at R*128 + ((4c+l4)^(R&7))*16
    auto ldA = [&](int buf, int mh) {
#pragma unroll
        for (int m = 0; m < 4; ++m)
#pragma unroll
            for (int c = 0; c < 2; ++c)
                a[m][c] = *(const bf16x8*)(lds + buf * 32768 + wr * 16384 +
                                           (mh * 64 + m * 16 + l15) * 128 +
                                           ((c * 4 + l4) ^ (l15 & 7)) * 16);
    };
    auto ldB = [&](int buf, int nh, bf16x8(&b)[2][2]) {
#pragma unroll
        for (int n = 0; n < 2; ++n)
#pragma unroll
            for (int c = 0; c < 2; ++c)
                b[n][c] = *(const bf16x8*)(lds + 65536 + buf * 32768 + (wc >> 1) * 16384 +
                                           ((wc & 1) * 64 + nh * 32 + n * 16 + l15) * 128 +
                                           ((c * 4 + l4) ^ (l15 & 7)) * 16);
    };
    auto mmac = [&](int mh, int nh, bf16x8(&b)[2][2]) {
        __builtin_amdgcn_s_setprio(1);
#pragma unroll
        for (int m = 0; m < 4; ++m)
#pragma unroll
            for (int n = 0; n < 2; ++n)
#pragma unroll
                for (int c = 0; c < 2; ++c)
                    acc[mh * 4 + m][nh * 2 + n] = __builtin_amdgcn_mfma_f32_16x16x32_bf16(
                        a[m][c], b[n][c], acc[mh * 4 + m][nh * 2 + n], 0, 0, 0);
        __builtin_amdgcn_s_setprio(0);
    };

    // prologue: tile0 all 4 half-tiles + tile1 Bh0, Ah0 (12 loads); leave tile1's in flight
    stageA(0, 0, 0);
    stageA(0, 1, 0);
    stageB(0, 0, 0);
    stageB(0, 1, 0);
    stageB(1, 0, 1);
    stageA(1, 0, 1);
    WAIT_VM4();
    BAR();

    for (int tt = 0; tt < NT; ++tt) {
        const int cur = tt & 1;
        // phase 0: quadrant (mh=0, nh=0); stage Ah1 for t+1 (idle buffer)
        ldA(cur, 0);
        ldB(cur, 0, b0);
        if (tt + 1 < NT) stageA(cur ^ 1, 1, tt + 1);
        BAR();
        WAIT_LGKM0();
        mmac(0, 0, b0);
        BAR();
        // phase 1: (0,1); stage Bh1 for t+1 (idle buffer)
        ldB(cur, 1, b1);
        if (tt + 1 < NT) stageB(cur ^ 1, 1, tt + 1);
        BAR();
        WAIT_LGKM0();
        mmac(0, 1, b1);
        BAR();
        // phase 2: (1,1); stage Bh0 for t+2 (live buffer, B reads done at p1)
        ldA(cur, 1);
        if (tt + 2 < NT) stageB(cur, 0, tt + 2);
        BAR();
        WAIT_LGKM0();
        mmac(1, 1, b1);
        BAR();
        // phase 3: (1,0); stage Ah0 for t+2 (live buffer, A reads done at p2)
        if (tt + 2 < NT) stageA(cur, 0, tt + 2);
        BAR();
        WAIT_LGKM0();
        mmac(1, 0, b0);
        // counted vmcnt: t+1 fully landed, t+2's Bh0/Ah0 (4 loads) stay in flight
        if (tt + 2 < NT) {
            WAIT_VM4();
        } else {
            WAIT_VM0();  // tail: drain everything
        }
        BAR();
    }

    // epilogue: C/D layout col = lane&15, row = (lane>>4)*4 + i
#pragma unroll
    for (int n = 0; n < 4; ++n) {
        const int col = bcol + wc * 64 + n * 16 + l15;
        const float bv = bias[col];
#pragma unroll
        for (int m = 0; m < 8; ++m) {
            const int row0 = brow + wr * 128 + m * 16 + l4 * 4;
            const f32x4 v = acc[m][n];
#pragma unroll
            for (int i = 0; i < 4; ++i)
                C[(size_t)(row0 + i) * N + col] = v[i] + bv;
        }
    }
}

// ---------------------------------------------------------------------------
extern "C" void kernel_launch(void* const* d_in, const int* in_sizes, int n_in,
                              void* d_out, int out_size, void* d_ws, size_t ws_size,
                              hipStream_t stream) {
    const float* x = (const float*)d_in[0];
    const float* Wa = (const float*)d_in[1];
    const float* Wb = (const float*)d_in[2];
    const float* Wc = (const float*)d_in[3];
    const float* Wd = (const float*)d_in[4];
    const float* bias = (const float*)d_in[5];
    float* out = (float*)d_out;

    const int M = 8192, N = 4096, K = 4096;

    bf16_t* xb = (bf16_t*)d_ws;       // [M][K] bf16
    bf16_t* Mt = xb + (size_t)M * K;  // [N][K] bf16

    cvt_x_kernel<<<4096, 256, 0, stream>>>(x, xb, (M * K) / 4);
    pack_w_kernel<<<dim3(64, 64), 256, 0, stream>>>(Wa, Wb, Wc, Wd, Mt);

    (void)hipFuncSetAttribute((const void*)qgemm_kernel,
                              hipFuncAttributeMaxDynamicSharedMemorySize, 131072);
    qgemm_kernel<<<dim3((M / 256) * (N / 256)), 512, 131072, stream>>>(xb, Mt, bias, out);
}